// Round 3
// baseline (775.142 us; speedup 1.0000x reference)
//
#include <hip/hip_runtime.h>
#include <math.h>

#define HDIM 60
#define EPSC 0.01f
#define ALPHAC 0.1f

// ---------------------------------------------------------------------------
// Kernel 1: compute h_0 = ICNN(Xref) once into workspace (single tiny block).
// ---------------------------------------------------------------------------
__global__ void dho_h0_kernel(const float* __restrict__ Xref,
                              const float* __restrict__ W1, const float* __restrict__ b1,
                              const float* __restrict__ W2, const float* __restrict__ b2,
                              const float* __restrict__ W3, const float* __restrict__ b3,
                              const float* __restrict__ Wim2, const float* __restrict__ Wim3,
                              float* __restrict__ h0out)
{
    __shared__ float z1s[HDIM];
    __shared__ float z2s[HDIM];
    const int t = threadIdx.x;
    const float x0 = Xref[0], x1 = Xref[1];
    if (t < HDIM) {
        float a = W1[2 * t] * x0 + W1[2 * t + 1] * x1 + b1[t];
        float e = expf(-fabsf(a));
        z1s[t] = logf(1.0f + e) + fmaxf(a, 0.0f);
    }
    __syncthreads();
    if (t < HDIM) {
        float a = b2[t] + Wim2[2 * t] * x0 + Wim2[2 * t + 1] * x1;
        for (int i = 0; i < HDIM; ++i) a += W2[t * HDIM + i] * z1s[i];
        float e = expf(-fabsf(a));
        z2s[t] = logf(1.0f + e) + fmaxf(a, 0.0f);
    }
    __syncthreads();
    if (t == 0) {
        float a = b3[0] + Wim3[0] * x0 + Wim3[1] * x1;
        for (int j = 0; j < HDIM; ++j) a += W3[j] * z2s[j];
        float e = expf(-fabsf(a));
        h0out[0] = logf(1.0f + e) + fmaxf(a, 0.0f);
    }
}

// pair swap via DPP quad_perm [1,0,3,2]: lane 2k <-> 2k+1, pure VALU, no LDS
__device__ __forceinline__ float pair_swap(float v) {
    int i = __builtin_amdgcn_mov_dpp(__float_as_int(v), 0xB1, 0xF, 0xF, true);
    return __int_as_float(i);
}

// ---------------------------------------------------------------------------
// Kernel 2: TWO lanes per sample. Even lane owns i in [0,32), odd lane owns
// i in [32,60) (padded to 32 with zeroed z1 slots; pad chunk aliases a safe
// in-bounds address and its contribution is exactly 0). Per-lane live state
// z1[32]+g1acc[32]+row[32] fits comfortably in VGPRs -> no AGPR round-trips,
// ~4 waves/SIMD. a2 and epilogue sums combine across the pair with DPP.
// ---------------------------------------------------------------------------
__global__ __launch_bounds__(256, 3) void dho_main_kernel(
    const float* __restrict__ X, const float* __restrict__ U,
    const float* __restrict__ W1, const float* __restrict__ b1,
    const float* __restrict__ W2, const float* __restrict__ b2,
    const float* __restrict__ W3,
    const float* __restrict__ Wim2,
    const float* __restrict__ W_fnn, const float* __restrict__ W_gnn,
    const float* __restrict__ b_gnn, const float* __restrict__ b3,
    const float* __restrict__ Wim3, const float* __restrict__ Xref,
    const float* __restrict__ h0p,
    float* __restrict__ out, int N)
{
    const int tid   = blockIdx.x * 256 + threadIdx.x;
    const int total = 2 * N;
    const int tcl   = tid < total ? tid : total - 1;   // clamp, keep uniform flow
    const int n     = tcl >> 1;
    const int p     = tcl & 1;

    const float2 x = ((const float2*)X)[n];
    const float  u = U[n];

    // ---- layer 1: own 32 of the 60 hidden units ----
    // global index map: p==0 -> i=l (l=0..31); p==1 -> i=32+l for l<28, pad for l>=28
    float z1[32];
#pragma unroll
    for (int l = 0; l < 32; ++l) {
        const int i = (l < 28) ? (32 * p + l) : l;       // always in [0,60)
        float2 w = ((const float2*)W1)[i];
        float a  = w.x * x.x + w.y * x.y + b1[i];
        float e  = __expf(-fabsf(a));
        float sp = __logf(1.0f + e) + fmaxf(a, 0.0f);
        z1[l] = (l >= 28 && p) ? 0.0f : sp;              // zero the pad slots
    }

    float g1[32];
#pragma unroll
    for (int l = 0; l < 32; ++l) g1[l] = 0.0f;

    float a3acc = 0.0f, q0 = 0.0f, q1 = 0.0f;

#pragma unroll 1
    for (int j = 0; j < HDIM; ++j) {
        const float* row = W2 + j * HDIM;
        const float* rl  = row + p * 32;                 // own half (floats 0..27 / 32..59)
        float4 r[8];
#pragma unroll
        for (int c = 0; c < 7; ++c) r[c] = ((const float4*)rl)[c];
        r[7] = *(const float4*)(row + 28);               // uniform addr; pad for p==1

        // forward partial dot over own half
        float s0 = 0.0f, s1a = 0.0f, s2a = 0.0f, s3a = 0.0f;
#pragma unroll
        for (int c = 0; c < 8; ++c) {
            s0  += r[c].x * z1[4 * c + 0];
            s1a += r[c].y * z1[4 * c + 1];
            s2a += r[c].z * z1[4 * c + 2];
            s3a += r[c].w * z1[4 * c + 3];
        }
        float psum = (s0 + s1a) + (s2a + s3a);
        float wi0 = Wim2[2 * j], wi1 = Wim2[2 * j + 1];
        float a2 = psum + pair_swap(psum) + b2[j] + wi0 * x.x + wi1 * x.y;

        // softplus + sigmoid (duplicated on both lanes — free under lockstep)
        float e   = __expf(-fabsf(a2));
        float inv = __builtin_amdgcn_rcpf(1.0f + e);
        float z2  = __logf(1.0f + e) + fmaxf(a2, 0.0f);
        float s2  = (a2 >= 0.0f ? 1.0f : e) * inv;

        float w3j = W3[j];
        a3acc += w3j * z2;
        float tj = w3j * s2;
        q0 += tj * wi0;
        q1 += tj * wi1;

        // backward: own half of g1 += tj * row  (pad slots get garbage*0 later)
#pragma unroll
        for (int c = 0; c < 8; ++c) {
            g1[4 * c + 0] += tj * r[c].x;
            g1[4 * c + 1] += tj * r[c].y;
            g1[4 * c + 2] += tj * r[c].z;
            g1[4 * c + 3] += tj * r[c].w;
        }
    }

    // ---- output layer (duplicated) ----
    const float wim3_0 = Wim3[0], wim3_1 = Wim3[1];
    float a3   = a3acc + b3[0] + wim3_0 * x.x + wim3_1 * x.y;
    float e3   = __expf(-fabsf(a3));
    float inv3 = __builtin_amdgcn_rcpf(1.0f + e3);
    float hX   = __logf(1.0f + e3) + fmaxf(a3, 0.0f);
    float s3   = (a3 >= 0.0f ? 1.0f : e3) * inv3;

    float h = hX - h0p[0];
    float sigma, sigp;
    if (h >= 1.0f)      { sigma = h - 0.5f;     sigp = 1.0f; }
    else if (h > 0.0f)  { sigma = 0.5f * h * h; sigp = h;    }
    else                { sigma = 0.0f;         sigp = 0.0f; }

    float dx0 = x.x - Xref[0], dx1 = x.y - Xref[1];
    float V = sigma + EPSC * (dx0 * dx0 + dx1 * dx1);

    // ---- backprop through layer 1 over own half, then pair-combine ----
    float sum0 = 0.0f, sum1 = 0.0f;
#pragma unroll
    for (int l = 0; l < 32; ++l) {
        const int i = (l < 28) ? (32 * p + l) : l;
        float2 w = ((const float2*)W1)[i];
        float s1v = 1.0f - __expf(-z1[l]);   // sigmoid(a1); =0 on pad slots (z1=0)
        float c   = g1[l] * s1v;
        sum0 += c * w.x;
        sum1 += c * w.y;
    }
    sum0 += pair_swap(sum0);
    sum1 += pair_swap(sum1);

    float dh0 = s3 * (wim3_0 + q0 + sum0);
    float dh1 = s3 * (wim3_1 + q1 + sum1);

    float dV0 = sigp * dh0 + 2.0f * EPSC * dx0;
    float dV1 = sigp * dh1 + 2.0f * EPSC * dx1;

    // ---- dynamics + correction (duplicated) ----
    float f0  = W_fnn[0] * x.x + W_fnn[1] * x.y;
    float f1  = W_fnn[2] * x.x + W_fnn[3] * x.y;
    float gg0 = W_gnn[0] * x.x + W_gnn[1] * x.y + b_gnn[0];
    float gg1 = W_gnn[2] * x.x + W_gnn[3] * x.y + b_gnn[1];

    float sc  = dV0 * f0 + dV1 * f1 + ALPHAC * V - fabsf(dV0 * gg0 + dV1 * gg1);
    float nrm = dV0 * dV0 + dV1 * dV1;
    float rr  = fmaxf(sc, 0.0f) * __builtin_amdgcn_rcpf(nrm);

    float o0 = f0 - dV0 * rr + gg0 * u;
    float o1 = f1 - dV1 * rr + gg1 * u;

    // lane stores its own component: out flat index 2n+p == tid
    if (tid < total) out[tid] = p ? o1 : o0;
}

extern "C" void kernel_launch(void* const* d_in, const int* in_sizes, int n_in,
                              void* d_out, int out_size, void* d_ws, size_t ws_size,
                              hipStream_t stream) {
    // 0:X 1:U 2:Xref 3:W_fnn 4:W_gnn 5:b_gnn 6:W1 7:b1 8:W2 9:b2 10:W3 11:b3 12:Wim2 13:Wim3
    const float* X     = (const float*)d_in[0];
    const float* U     = (const float*)d_in[1];
    const float* Xref  = (const float*)d_in[2];
    const float* W_fnn = (const float*)d_in[3];
    const float* W_gnn = (const float*)d_in[4];
    const float* b_gnn = (const float*)d_in[5];
    const float* W1    = (const float*)d_in[6];
    const float* b1    = (const float*)d_in[7];
    const float* W2    = (const float*)d_in[8];
    const float* b2    = (const float*)d_in[9];
    const float* W3    = (const float*)d_in[10];
    const float* b3    = (const float*)d_in[11];
    const float* Wim2  = (const float*)d_in[12];
    const float* Wim3  = (const float*)d_in[13];

    const int N = in_sizes[0] / 2;
    float* h0  = (float*)d_ws;
    float* out = (float*)d_out;

    dho_h0_kernel<<<1, 64, 0, stream>>>(Xref, W1, b1, W2, b2, W3, b3, Wim2, Wim3, h0);

    const int threads = 2 * N;
    const int blocks  = (threads + 255) / 256;
    dho_main_kernel<<<blocks, 256, 0, stream>>>(
        X, U, W1, b1, W2, b2, W3, Wim2,
        W_fnn, W_gnn, b_gnn, b3, Wim3, Xref, h0,
        out, N);
}

// Round 4
// 314.580 us; speedup vs baseline: 2.4641x; 2.4641x over previous
//
#include <hip/hip_runtime.h>
#include <math.h>

#define HDIM 60
#define EPSC 0.01f
#define ALPHAC 0.1f

// ---------------------------------------------------------------------------
// Kernel 1: compute h_0 = ICNN(Xref) once into workspace (single tiny block).
// ---------------------------------------------------------------------------
__global__ void dho_h0_kernel(const float* __restrict__ Xref,
                              const float* __restrict__ W1, const float* __restrict__ b1,
                              const float* __restrict__ W2, const float* __restrict__ b2,
                              const float* __restrict__ W3, const float* __restrict__ b3,
                              const float* __restrict__ Wim2, const float* __restrict__ Wim3,
                              float* __restrict__ h0out)
{
    __shared__ float z1s[HDIM];
    __shared__ float z2s[HDIM];
    const int t = threadIdx.x;
    const float x0 = Xref[0], x1 = Xref[1];
    if (t < HDIM) {
        float a = W1[2 * t] * x0 + W1[2 * t + 1] * x1 + b1[t];
        float e = expf(-fabsf(a));
        z1s[t] = logf(1.0f + e) + fmaxf(a, 0.0f);
    }
    __syncthreads();
    if (t < HDIM) {
        float a = b2[t] + Wim2[2 * t] * x0 + Wim2[2 * t + 1] * x1;
        for (int i = 0; i < HDIM; ++i) a += W2[t * HDIM + i] * z1s[i];
        float e = expf(-fabsf(a));
        z2s[t] = logf(1.0f + e) + fmaxf(a, 0.0f);
    }
    __syncthreads();
    if (t == 0) {
        float a = b3[0] + Wim3[0] * x0 + Wim3[1] * x1;
        for (int j = 0; j < HDIM; ++j) a += W3[j] * z2s[j];
        float e = expf(-fabsf(a));
        h0out[0] = logf(1.0f + e) + fmaxf(a, 0.0f);
    }
}

// ---------------------------------------------------------------------------
// Kernel 2: one thread per sample (R2 structure). Weights staged in LDS:
// all 64 lanes read the SAME LDS address -> broadcast, no bank conflicts,
// no dependence on the compiler's global-load scalarization. W2 row is held
// in 15 float4 regs across the softplus so one load serves fwd AND bwd FMAs.
// Live set ~210 floats < 256 -> launch_bounds(256,2) gives a 256-reg unified
// budget per wave: everything should be arch VGPRs, no AGPR round-trips
// (R2's 1.6x issue inflation).
// ---------------------------------------------------------------------------
__global__ __launch_bounds__(256, 2) void dho_main_kernel(
    const float* __restrict__ X, const float* __restrict__ U,
    const float* __restrict__ W1, const float* __restrict__ b1,
    const float* __restrict__ W2, const float* __restrict__ b2,
    const float* __restrict__ W3,
    const float* __restrict__ Wim2,
    const float* __restrict__ W_fnn, const float* __restrict__ W_gnn,
    const float* __restrict__ b_gnn, const float* __restrict__ b3,
    const float* __restrict__ Wim3, const float* __restrict__ Xref,
    const float* __restrict__ h0p,
    float* __restrict__ out, int N)
{
    __shared__ __align__(16) float sW2[HDIM * HDIM];   // 14400 B, row-major
    __shared__ float4 sW1b[HDIM];                      // (W1[i,0], W1[i,1], b1[i], 0)
    __shared__ float4 sJ[HDIM];                        // (b2[j], Wim2[j,0], Wim2[j,1], W3[j])

    const int t = threadIdx.x;
    for (int k = t; k < HDIM * HDIM; k += 256) sW2[k] = W2[k];
    if (t < HDIM) {
        sW1b[t] = make_float4(W1[2 * t], W1[2 * t + 1], b1[t], 0.0f);
        sJ[t]   = make_float4(b2[t], Wim2[2 * t], Wim2[2 * t + 1], W3[t]);
    }
    __syncthreads();

    const int n_raw = blockIdx.x * 256 + t;
    const int n = n_raw < N ? n_raw : N - 1;    // clamp: uniform control flow

    const float2 x = ((const float2*)X)[n];
    const float  u = U[n];

    // ---- layer 1: z1 = softplus(W1 x + b1) ----
    float z1[HDIM];
#pragma unroll
    for (int i = 0; i < HDIM; ++i) {
        float4 w = sW1b[i];
        float a  = w.x * x.x + w.y * x.y + w.z;
        float e  = __expf(-fabsf(a));
        z1[i] = __logf(1.0f + e) + fmaxf(a, 0.0f);
    }

    // ---- layer 2 fwd + reverse-mode accumulation, one LDS row load per j ----
    float g1[HDIM];
#pragma unroll
    for (int i = 0; i < HDIM; ++i) g1[i] = 0.0f;

    float a3acc = 0.0f, q0 = 0.0f, q1 = 0.0f;

#pragma unroll 1
    for (int j = 0; j < HDIM; ++j) {
        const float4* rp = (const float4*)(&sW2[j * HDIM]);
        float4 r[15];
#pragma unroll
        for (int c = 0; c < 15; ++c) r[c] = rp[c];      // ds_read_b128 x15, broadcast
        float4 pj = sJ[j];                              // b2, wi0, wi1, w3

        float acc0 = 0.0f, acc1 = 0.0f, acc2 = 0.0f, acc3 = 0.0f;
#pragma unroll
        for (int c = 0; c < 15; ++c) {
            acc0 += r[c].x * z1[4 * c + 0];
            acc1 += r[c].y * z1[4 * c + 1];
            acc2 += r[c].z * z1[4 * c + 2];
            acc3 += r[c].w * z1[4 * c + 3];
        }
        float a2 = (acc0 + acc1) + (acc2 + acc3) + pj.x + pj.y * x.x + pj.z * x.y;

        float e   = __expf(-fabsf(a2));
        float inv = __builtin_amdgcn_rcpf(1.0f + e);
        float z2  = __logf(1.0f + e) + fmaxf(a2, 0.0f);
        float s2  = (a2 >= 0.0f ? 1.0f : e) * inv;

        a3acc += pj.w * z2;
        float tj = pj.w * s2;
        q0 += tj * pj.y;
        q1 += tj * pj.z;
#pragma unroll
        for (int c = 0; c < 15; ++c) {
            g1[4 * c + 0] += tj * r[c].x;
            g1[4 * c + 1] += tj * r[c].y;
            g1[4 * c + 2] += tj * r[c].z;
            g1[4 * c + 3] += tj * r[c].w;
        }
    }

    // ---- output layer ----
    const float wim3_0 = Wim3[0], wim3_1 = Wim3[1];
    float a3   = a3acc + b3[0] + wim3_0 * x.x + wim3_1 * x.y;
    float e3   = __expf(-fabsf(a3));
    float inv3 = __builtin_amdgcn_rcpf(1.0f + e3);
    float hX   = __logf(1.0f + e3) + fmaxf(a3, 0.0f);
    float s3   = (a3 >= 0.0f ? 1.0f : e3) * inv3;

    float h = hX - h0p[0];
    float sigma, sigp;
    if (h >= 1.0f)      { sigma = h - 0.5f;     sigp = 1.0f; }
    else if (h > 0.0f)  { sigma = 0.5f * h * h; sigp = h;    }
    else                { sigma = 0.0f;         sigp = 0.0f; }

    float dx0 = x.x - Xref[0], dx1 = x.y - Xref[1];
    float V = sigma + EPSC * (dx0 * dx0 + dx1 * dx1);

    // ---- backprop through layer 1 ----
    float sum0 = 0.0f, sum1 = 0.0f;
#pragma unroll
    for (int i = 0; i < HDIM; ++i) {
        float4 w  = sW1b[i];
        float s1v = 1.0f - __expf(-z1[i]);   // sigmoid(a1) = 1 - exp(-softplus(a1))
        float c   = g1[i] * s1v;
        sum0 += c * w.x;
        sum1 += c * w.y;
    }
    float dh0 = s3 * (wim3_0 + q0 + sum0);
    float dh1 = s3 * (wim3_1 + q1 + sum1);

    float dV0 = sigp * dh0 + 2.0f * EPSC * dx0;
    float dV1 = sigp * dh1 + 2.0f * EPSC * dx1;

    // ---- dynamics + correction ----
    float f0  = W_fnn[0] * x.x + W_fnn[1] * x.y;
    float f1  = W_fnn[2] * x.x + W_fnn[3] * x.y;
    float gg0 = W_gnn[0] * x.x + W_gnn[1] * x.y + b_gnn[0];
    float gg1 = W_gnn[2] * x.x + W_gnn[3] * x.y + b_gnn[1];

    float sc  = dV0 * f0 + dV1 * f1 + ALPHAC * V - fabsf(dV0 * gg0 + dV1 * gg1);
    float nrm = dV0 * dV0 + dV1 * dV1;
    float rr  = fmaxf(sc, 0.0f) * __builtin_amdgcn_rcpf(nrm);

    float o0 = f0 - dV0 * rr + gg0 * u;
    float o1 = f1 - dV1 * rr + gg1 * u;
    if (n_raw < N) ((float2*)out)[n] = make_float2(o0, o1);
}

extern "C" void kernel_launch(void* const* d_in, const int* in_sizes, int n_in,
                              void* d_out, int out_size, void* d_ws, size_t ws_size,
                              hipStream_t stream) {
    // 0:X 1:U 2:Xref 3:W_fnn 4:W_gnn 5:b_gnn 6:W1 7:b1 8:W2 9:b2 10:W3 11:b3 12:Wim2 13:Wim3
    const float* X     = (const float*)d_in[0];
    const float* U     = (const float*)d_in[1];
    const float* Xref  = (const float*)d_in[2];
    const float* W_fnn = (const float*)d_in[3];
    const float* W_gnn = (const float*)d_in[4];
    const float* b_gnn = (const float*)d_in[5];
    const float* W1    = (const float*)d_in[6];
    const float* b1    = (const float*)d_in[7];
    const float* W2    = (const float*)d_in[8];
    const float* b2    = (const float*)d_in[9];
    const float* W3    = (const float*)d_in[10];
    const float* b3    = (const float*)d_in[11];
    const float* Wim2  = (const float*)d_in[12];
    const float* Wim3  = (const float*)d_in[13];

    const int N = in_sizes[0] / 2;
    float* h0  = (float*)d_ws;
    float* out = (float*)d_out;

    dho_h0_kernel<<<1, 64, 0, stream>>>(Xref, W1, b1, W2, b2, W3, b3, Wim2, Wim3, h0);

    const int blocks = (N + 255) / 256;
    dho_main_kernel<<<blocks, 256, 0, stream>>>(
        X, U, W1, b1, W2, b2, W3, Wim2,
        W_fnn, W_gnn, b_gnn, b3, Wim3, Xref, h0,
        out, N);
}